// Round 6
// baseline (393.582 us; speedup 1.0000x reference)
//
#include <hip/hip_runtime.h>
#include <math.h>
#include <stdint.h>

#define NANCH 49104
#define NCLS 80
#define KSEL 100
#define NFLAT (NCLS * KSEL)
#define PREDC 84
#define NB 8
#define ECAP 128
#define TOTF4 (NB * NANCH * (PREDC / 4))   // 8,249,472 float4s
#define BATF4 (NANCH * (PREDC / 4))        // 1,031,184 float4s per batch
#define PCAP 32                             // per-class per-part slice cap
#define OCAP 256                            // per-(b,c) overflow pool cap
#define LISTCAP 4096                        // LDS candidate list cap (overlaid on hist)
// logit(0.9): candidates are scores > 0.9; per-class top-100 threshold ~0.947 here
#define THRL 2.1972246f

struct DimsTable { float d[5][9][2]; };
struct KT { uint32_t key; int tie; };

__device__ __forceinline__ uint32_t f2key(float f) {
    uint32_t u = __float_as_uint(f);
    return u ^ (uint32_t((int32_t)u >> 31) | 0x80000000u);
}
__device__ __forceinline__ float key2f(uint32_t k) {
    uint32_t u = (k & 0x80000000u) ? (k ^ 0x80000000u) : ~k;
    return __uint_as_float(u);
}
__device__ __forceinline__ float sigm(float x) { return 1.0f / (1.0f + expf(-x)); }

__device__ __forceinline__ void decode_box(const float4 pv, int n,
                                           const DimsTable& dt, float box[4]) {
    int lev, base, fw, stride;
    if (n < 36864)      { lev = 0; base = 0;     fw = 64; stride = 8;   }
    else if (n < 46080) { lev = 1; base = 36864; fw = 32; stride = 16;  }
    else if (n < 48384) { lev = 2; base = 46080; fw = 16; stride = 32;  }
    else if (n < 48960) { lev = 3; base = 48384; fw = 8;  stride = 64;  }
    else                { lev = 4; base = 48960; fw = 4;  stride = 128; }
    int i = n - base;
    int k = i % 9;
    int cell = i / 9;
    int xq = cell % fw, yq = cell / fw;
    float cx = ((float)xq + 0.5f) * (float)stride;
    float cy = ((float)yq + 0.5f) * (float)stride;
    float aw = dt.d[lev][k][0];
    float ah = dt.d[lev][k][1];
    float tx = __fmul_rn(pv.x, 0.1f);
    float ty = __fmul_rn(pv.y, 0.1f);
    float tw = __fmul_rn(pv.z, 0.2f);
    float th = __fmul_rn(pv.w, 0.2f);
    float px = __fadd_rn(__fmul_rn(tx, aw), cx);
    float py = __fadd_rn(__fmul_rn(ty, ah), cy);
    float pw = __fmul_rn(expf(tw), aw);
    float ph = __fmul_rn(expf(th), ah);
    float hw = __fmul_rn(pw, 0.5f);
    float hh = __fmul_rn(ph, 0.5f);
    box[0] = __fsub_rn(px, hw);
    box[1] = __fsub_rn(py, hh);
    box[2] = __fadd_rn(px, hw);
    box[3] = __fadd_rn(py, hh);
}

struct SelSh {
    int hist[4][2048];        // 32 KB; ALSO overlaid as uint2 list[4096] in nms_sel
    int suffix[256];
    uint32_t candKey[KSEL];
    int candIdx[KSEL];
    uint32_t eIdx[ECAP];
    uint32_t sKey[KSEL];
    int sIdx[KSEL];
    int cntG, cntE, krem, newkrem, digit, flast, rmin;
    uint32_t prefix, thrKey;
};

// Exact top-min(K,N) by (key desc, tie asc); fills sh.sKey/sIdx sorted. 256 thr.
template <typename G>
__device__ int block_select(G get, int N, int K, SelSh& sh) {
    const int tid = threadIdx.x;
    const int wid = tid >> 6;
    int Ksel = (N < K) ? N : K;
    if (Ksel <= 0) return 0;

    if (N <= K) {                     // take everything, just sort
        if (tid < N) { KT e = get(tid); sh.candKey[tid] = e.key; sh.candIdx[tid] = e.tie; }
        __syncthreads();
        if (tid < N) {
            uint32_t mk = sh.candKey[tid]; int mi = sh.candIdx[tid];
            int rank = 0;
            for (int j = 0; j < N; ++j) {
                uint32_t kj = sh.candKey[j]; int ij = sh.candIdx[j];
                rank += (kj > mk) || (kj == mk && ij < mi);
            }
            sh.sKey[rank] = mk; sh.sIdx[rank] = mi;
        }
        __syncthreads();
        return Ksel;
    }

    if (tid == 0) { sh.krem = K; sh.prefix = 0; }
    for (int pass = 0; pass < 3; ++pass) {
        const int bins   = (pass == 2) ? 1024 : 2048;
        const int dshift = (pass == 0) ? 21 : (pass == 1 ? 10 : 0);
        const int fshift = (pass == 1) ? 21 : 10;
        const int dmask  = bins - 1;
        const bool multi = (pass == 0);
        if (multi) { for (int j = tid; j < 4 * 2048; j += 256) ((int*)sh.hist)[j] = 0; }
        else       { for (int j = tid; j < bins; j += 256) sh.hist[0][j] = 0; }
        __syncthreads();
        const uint32_t pref = sh.prefix;
        for (int i = tid; i < N; i += 256) {
            uint32_t key = get(i).key;
            if (pass == 0) {
                atomicAdd(&sh.hist[wid][(key >> dshift) & dmask], 1);
            } else if ((key >> fshift) == pref) {
                atomicAdd(&sh.hist[0][(key >> dshift) & dmask], 1);
            }
        }
        __syncthreads();
        if (multi) {
            for (int j = tid; j < bins; j += 256)
                sh.hist[0][j] += sh.hist[1][j] + sh.hist[2][j] + sh.hist[3][j];
            __syncthreads();
        }
        const int cpb = bins / 256;
        const int base = tid * cpb;
        int lsum = 0;
        for (int j = 0; j < cpb; ++j) lsum += sh.hist[0][base + j];
        // parallel suffix sum (Hillis-Steele)
        sh.suffix[tid] = lsum;
        __syncthreads();
        for (int off = 1; off < 256; off <<= 1) {
            int v = (tid + off < 256) ? sh.suffix[tid + off] : 0;
            __syncthreads();
            sh.suffix[tid] += v;
            __syncthreads();
        }
        {
            int cum = sh.suffix[tid] - lsum;
            const int krem = sh.krem;
            for (int j = cpb - 1; j >= 0; --j) {
                int cnt = sh.hist[0][base + j];
                if (cnt > 0 && cum < krem && cum + cnt >= krem) {
                    sh.digit = base + j;
                    sh.newkrem = krem - cum;
                }
                cum += cnt;
            }
        }
        __syncthreads();
        if (tid == 0) {
            sh.krem = sh.newkrem;
            if (pass == 0)      sh.prefix = (uint32_t)sh.digit;
            else if (pass == 1) sh.prefix = (sh.prefix << 11) | (uint32_t)sh.digit;
            else                sh.thrKey = (sh.prefix << 10) | (uint32_t)sh.digit;
        }
        __syncthreads();
    }

    if (tid == 0) { sh.cntG = 0; sh.cntE = 0; }
    __syncthreads();
    const uint32_t thr = sh.thrKey;
    for (int i = tid; i < N; i += 256) {
        KT e = get(i);
        if (e.key > thr) {
            int g = atomicAdd(&sh.cntG, 1);
            sh.candKey[g] = e.key; sh.candIdx[g] = e.tie;
        } else if (e.key == thr) {
            int idx = atomicAdd(&sh.cntE, 1);
            if (idx < ECAP) sh.eIdx[idx] = (uint32_t)e.tie;
        }
    }
    __syncthreads();
    const int need = sh.krem;
    const int nG = K - need;
    if (sh.cntE <= ECAP) {
        const int ce = sh.cntE;
        if (tid < ce) {
            uint32_t my = sh.eIdx[tid];
            int rank = 0;
            for (int j = 0; j < ce; ++j) rank += (sh.eIdx[j] < my);
            if (rank < need) { sh.candKey[nG + rank] = thr; sh.candIdx[nG + rank] = (int)my; }
        }
    } else {
        if (tid == 0) sh.flast = -1;
        __syncthreads();
        for (int t = 0; t < need; ++t) {
            if (tid == 0) sh.rmin = 0x7FFFFFFF;
            __syncthreads();
            const int fl = sh.flast;
            int lmin = 0x7FFFFFFF;
            for (int i = tid; i < N; i += 256) {
                KT e = get(i);
                if (e.key == thr && e.tie > fl) lmin = min(lmin, e.tie);
            }
            atomicMin(&sh.rmin, lmin);
            __syncthreads();
            if (tid == 0) { sh.candKey[nG + t] = thr; sh.candIdx[nG + t] = sh.rmin; sh.flast = sh.rmin; }
            __syncthreads();
        }
    }
    __syncthreads();
    if (tid < K) {
        uint32_t mk = sh.candKey[tid]; int mi = sh.candIdx[tid];
        int rank = 0;
        for (int j = 0; j < K; ++j) {
            uint32_t kj = sh.candKey[j]; int ij = sh.candIdx[j];
            rank += (kj > mk) || (kj == mk && ij < mi);
        }
        sh.sKey[rank] = mk; sh.sIdx[rank] = mi;
    }
    __syncthreads();
    return Ksel;
}

// ---------- kernel 1: coalesced scan -> block-private slices (no hot atomics) --
__device__ __forceinline__ void procf4(float4 p, int v, int b,
                                       int* lcnt, uint2 (*buck)[PCAP],
                                       int* cnt, uint2* oflow) {
    uint32_t q = (uint32_t)v / 21u;
    uint32_t j = (uint32_t)v - q * 21u;
    if (j == 0u) return;
    bool c0 = p.x > THRL, c1 = p.y > THRL, c2 = p.z > THRL, c3 = p.w > THRL;
    if (!(c0 | c1 | c2 | c3)) return;
    uint32_t row = q - (uint32_t)b * (uint32_t)NANCH;
    int cbase = ((int)j - 1) * 4;
    float vv[4] = {p.x, p.y, p.z, p.w};
    bool pp[4] = {c0, c1, c2, c3};
#pragma unroll
    for (int k = 0; k < 4; ++k) {
        if (pp[k]) {
            int c = cbase + k;
            uint32_t key = f2key(sigm(vv[k]));
            int slot = atomicAdd(&lcnt[c], 1);
            if (slot < PCAP) {
                buck[c][slot] = make_uint2(key, row);
            } else {                       // rare overflow -> global pool
                int bc = b * NCLS + c;
                int gs = atomicAdd(&cnt[bc], 1);
                if (gs < OCAP) oflow[(size_t)bc * OCAP + gs] = make_uint2(key, row);
            }
        }
    }
}

__global__ __launch_bounds__(256) void cand_scan(const float4* __restrict__ predv,
                                                 uint2* __restrict__ cand2,
                                                 int* __restrict__ cnt2,
                                                 uint2* __restrict__ oflow,
                                                 int* __restrict__ cnt,
                                                 int P, int CH) {
    __shared__ uint2 buck[NCLS][PCAP];     // 20 KB
    __shared__ int lcnt[NCLS];

    const int tid = threadIdx.x;
    const int b = blockIdx.x / P;
    const int part = blockIdx.x - b * P;

    for (int j = tid; j < NCLS; j += 256) lcnt[j] = 0;
    __syncthreads();

    int s = b * BATF4 + part * CH;
    int e = b * BATF4 + BATF4;
    if (s + CH < e) e = s + CH;

    int v = s + tid;
    for (; v + 768 < e; v += 1024) {       // 4 independent loads in flight
        float4 a0 = predv[v];
        float4 a1 = predv[v + 256];
        float4 a2 = predv[v + 512];
        float4 a3 = predv[v + 768];
        procf4(a0, v,       b, lcnt, buck, cnt, oflow);
        procf4(a1, v + 256, b, lcnt, buck, cnt, oflow);
        procf4(a2, v + 512, b, lcnt, buck, cnt, oflow);
        procf4(a3, v + 768, b, lcnt, buck, cnt, oflow);
    }
    for (; v < e; v += 256)
        procf4(predv[v], v, b, lcnt, buck, cnt, oflow);
    __syncthreads();

    // write per-(b,c,part) counts (clamped) and slice contents
    if (tid < NCLS) {
        int lc = lcnt[tid];
        if (lc > PCAP) lc = PCAP;
        cnt2[((size_t)b * NCLS + tid) * P + part] = lc;
    }
    for (int x = tid; x < NCLS * PCAP; x += 256) {
        int c = x >> 5;                    // PCAP = 32
        int k = x & (PCAP - 1);
        int lc = lcnt[c];
        if (lc > PCAP) lc = PCAP;
        if (k < lc)
            cand2[(((size_t)b * NCLS + c) * P + part) * PCAP + k] = buck[c][k];
    }
}

// ---------- kernel 2: gather + exact rank-select top-100 + wave NMS ----------
__global__ __launch_bounds__(256) void nms_sel(const float* __restrict__ pred,
                                               const uint2* __restrict__ cand2,
                                               const int* __restrict__ cnt2,
                                               const uint2* __restrict__ oflow,
                                               const int* __restrict__ cnt,
                                               int P,
                                               float* __restrict__ cls_boxes,
                                               uint32_t* __restrict__ posKey,
                                               uint32_t* __restrict__ posFlat,
                                               int* __restrict__ posCnt,
                                               DimsTable dt) {
    __shared__ SelSh sh;
    const int c = blockIdx.x;
    const int b = blockIdx.y;
    const int tid = threadIdx.x;
    const int bc = b * NCLS + c;
    uint2* list = (uint2*)sh.hist;         // 4096 entries, overlaid on hist

    // gather counts + prefix sum (ascending, inclusive)
    int kt = (tid < P) ? cnt2[(size_t)bc * P + tid] : 0;
    sh.suffix[tid] = kt;
    __syncthreads();
    for (int off = 1; off < 256; off <<= 1) {
        int v = (tid >= off) ? sh.suffix[tid - off] : 0;
        __syncthreads();
        sh.suffix[tid] += v;
        __syncthreads();
    }
    const int excl = sh.suffix[tid] - kt;
    const int n0 = sh.suffix[255];
    const int of = cnt[bc];
    const int n = n0 + of;
    const bool fallback = (of > OCAP) || (n > LISTCAP) || (n < KSEL);

    if (!fallback) {
        if (kt > 0) {
            const uint2* src = cand2 + ((size_t)bc * P + tid) * PCAP;
            for (int j = 0; j < kt; ++j) list[excl + j] = src[j];
        }
        for (int x = tid; x < of; x += 256)
            list[n0 + x] = oflow[(size_t)bc * OCAP + x];
        __syncthreads();
        // exact rank select: rank by (key desc, row asc); ranks are unique
        for (int i = tid; i < n; i += 256) {
            uint2 e = list[i];
            int rank = 0;
#pragma unroll 4
            for (int j = 0; j < n; ++j) {
                uint2 o = list[j];
                rank += (o.x > e.x) || (o.x == e.x && o.y < e.y);
            }
            if (rank < KSEL) { sh.sKey[rank] = e.x; sh.sIdx[rank] = (int)e.y; }
        }
        __syncthreads();
    } else {
        // exact fallback: full strided scan (never taken on this data)
        const float* src = pred + (size_t)b * NANCH * PREDC + 4 + c;
        auto g = [src](int i) { KT e; e.key = f2key(sigm(src[(size_t)i * PREDC])); e.tie = i; return e; };
        block_select(g, NANCH, KSEL, sh);
    }

    if (tid < 64) {
        const int l = tid;
        uint32_t key0 = sh.sKey[l]; int n0i = sh.sIdx[l];
        float4 pv0 = reinterpret_cast<const float4*>(pred)[((size_t)b * NANCH + n0i) * (PREDC / 4) + 0];
        float b0[4]; decode_box(pv0, n0i, dt, b0);
        float area0 = __fmul_rn(__fsub_rn(b0[2], b0[0]), __fsub_rn(b0[3], b0[1]));
        int k0 = key2f(key0) > 0.05f;

        const bool has1 = (l + 64) < KSEL;
        uint32_t key1 = 0; int n1i = 0;
        float b1[4] = {0.f, 0.f, 0.f, 0.f}; float area1 = 0.f; int k1 = 0;
        if (has1) {
            key1 = sh.sKey[l + 64]; n1i = sh.sIdx[l + 64];
            float4 pv1 = reinterpret_cast<const float4*>(pred)[((size_t)b * NANCH + n1i) * (PREDC / 4) + 0];
            decode_box(pv1, n1i, dt, b1);
            area1 = __fmul_rn(__fsub_rn(b1[2], b1[0]), __fsub_rn(b1[3], b1[1]));
            k1 = key2f(key1) > 0.05f;
        }

        for (int i = 0; i < KSEL; ++i) {
            int kk; float c0, c1, c2, c3, ca;
            if (i < 64) { kk = k0; c0 = b0[0]; c1 = b0[1]; c2 = b0[2]; c3 = b0[3]; ca = area0; }
            else        { kk = k1; c0 = b1[0]; c1 = b1[1]; c2 = b1[2]; c3 = b1[3]; ca = area1; }
            const int sl = i & 63;
            int ki = __shfl(kk, sl);
            if (ki) {
                float ix0 = __shfl(c0, sl), iy0 = __shfl(c1, sl);
                float ix1 = __shfl(c2, sl), iy1 = __shfl(c3, sl);
                float ia  = __shfl(ca, sl);
                if (k0 && l > i) {
                    float x1 = fmaxf(ix0, b0[0]), y1 = fmaxf(iy0, b0[1]);
                    float x2 = fminf(ix1, b0[2]), y2 = fminf(iy1, b0[3]);
                    float iw = fmaxf(__fsub_rn(x2, x1), 0.0f);
                    float ih = fmaxf(__fsub_rn(y2, y1), 0.0f);
                    float inter = __fmul_rn(iw, ih);
                    float uni = __fsub_rn(__fadd_rn(ia, area0), inter);
                    if (__fdiv_rn(inter, fmaxf(uni, 1e-8f)) > 0.5f) k0 = 0;
                }
                if (k1 && (l + 64) > i) {
                    float x1 = fmaxf(ix0, b1[0]), y1 = fmaxf(iy0, b1[1]);
                    float x2 = fminf(ix1, b1[2]), y2 = fminf(iy1, b1[3]);
                    float iw = fmaxf(__fsub_rn(x2, x1), 0.0f);
                    float ih = fmaxf(__fsub_rn(y2, y1), 0.0f);
                    float inter = __fmul_rn(iw, ih);
                    float uni = __fsub_rn(__fadd_rn(ia, area1), inter);
                    if (__fdiv_rn(inter, fmaxf(uni, 1e-8f)) > 0.5f) k1 = 0;
                }
            }
        }

        reinterpret_cast<float4*>(cls_boxes)[(size_t)b * NFLAT + c * KSEL + l] =
            make_float4(b0[0], b0[1], b0[2], b0[3]);
        if (has1)
            reinterpret_cast<float4*>(cls_boxes)[(size_t)b * NFLAT + c * KSEL + l + 64] =
                make_float4(b1[0], b1[1], b1[2], b1[3]);

        unsigned long long m0 = __ballot(k0);
        unsigned long long m1 = __ballot(k1);
        int tot = __popcll(m0) + __popcll(m1);
        int base;
        if (l == 0) base = atomicAdd(&posCnt[b], tot);
        base = __shfl(base, 0);
        if (k0) {
            int off = __popcll(m0 & ((1ull << l) - 1));
            posKey[(size_t)b * NFLAT + base + off] = key0;
            posFlat[(size_t)b * NFLAT + base + off] = (uint32_t)(c * KSEL + l);
        }
        if (k1) {
            int off = __popcll(m0) + __popcll(m1 & ((1ull << l) - 1));
            posKey[(size_t)b * NFLAT + base + off] = key1;
            posFlat[(size_t)b * NFLAT + base + off] = (uint32_t)(c * KSEL + l + 64);
        }
    }
}

// ---------- kernel 3: per-batch final top-100 over compacted positives -------
__global__ __launch_bounds__(256) void final_sel(const float* __restrict__ cls_boxes,
                                                 const uint32_t* __restrict__ posKey,
                                                 const uint32_t* __restrict__ posFlat,
                                                 const int* __restrict__ posCnt,
                                                 float* __restrict__ out) {
    __shared__ SelSh sh;
    const int b = blockIdx.x;
    const int tid = threadIdx.x;
    int m = posCnt[b];
    if (m > NFLAT) m = NFLAT;
    const uint32_t* pk = posKey + (size_t)b * NFLAT;
    const uint32_t* pf = posFlat + (size_t)b * NFLAT;
    auto g = [pk, pf](int i) { KT e; e.key = pk[i]; e.tie = (int)pf[i]; return e; };
    int K = block_select(g, m, KSEL, sh);
    if (tid < KSEL) {
        float4 ob = make_float4(0.f, 0.f, 0.f, 0.f);
        float sv = 0.f, cv = 0.f;
        if (tid < K) {
            sv = key2f(sh.sKey[tid]);
            int flat = sh.sIdx[tid];
            ob = reinterpret_cast<const float4*>(cls_boxes)[(size_t)b * NFLAT + flat];
            cv = (float)(flat / KSEL);
        }
        reinterpret_cast<float4*>(out)[(size_t)b * KSEL + tid] = ob;
        out[NB * KSEL * 4 + b * KSEL + tid] = sv;
        out[NB * KSEL * 5 + b * KSEL + tid] = cv;
    }
    if (tid == 0) out[NB * KSEL * 6 + b] = (float)K;
}

// ---------- host launcher ----------------------------------------------------
extern "C" void kernel_launch(void* const* d_in, const int* in_sizes, int n_in,
                              void* d_out, int out_size, void* d_ws, size_t ws_size,
                              hipStream_t stream) {
    const float* pred = (const float*)d_in[1];
    float* out = (float*)d_out;

    DimsTable dt;
    const double areasd[5] = {1024.0, 4096.0, 16384.0, 65536.0, 262144.0};
    const double ratios[3] = {0.5, 1.0, 2.0};
    const double scales[3] = {1.0, pow(2.0, 1.0 / 3.0), pow(2.0, 2.0 / 3.0)};
    for (int l = 0; l < 5; ++l)
        for (int ri = 0; ri < 3; ++ri) {
            double ah = sqrt(areasd[l] / ratios[ri]);
            double aw = areasd[l] / ah;
            for (int si = 0; si < 3; ++si) {
                dt.d[l][ri * 3 + si][0] = (float)(aw * scales[si]);
                dt.d[l][ri * 3 + si][1] = (float)(ah * scales[si]);
            }
        }

    // pick parts-per-batch P from workspace size
    const size_t fixedB = 4096
        + (size_t)NB * NCLS * OCAP * 8        // oflow
        + (size_t)NB * NFLAT * 4 * 4          // cls_boxes
        + (size_t)NB * NFLAT * 4 * 2;         // posKey + posFlat
    int P = 64;                                // 13.5 MB total: proven-safe floor
    const int cands[3] = {256, 128, 64};
    for (int ci = 0; ci < 3; ++ci) {
        size_t tot = fixedB + (size_t)NB * NCLS * cands[ci] * (PCAP * 8 + 4);
        if (tot <= ws_size) { P = cands[ci]; break; }
    }
    const int CH = (BATF4 + P - 1) / P;

    // workspace layout
    char* wsb = (char*)d_ws;
    int* cnt = (int*)wsb;                                   // [640]
    int* posCnt = cnt + NB * NCLS;                          // [8]
    uint2* oflow = (uint2*)(wsb + 4096);                    // [640][OCAP]
    float* cls_boxes = (float*)((char*)oflow + (size_t)NB * NCLS * OCAP * 8);
    uint32_t* posKey = (uint32_t*)(cls_boxes + (size_t)NB * NFLAT * 4);
    uint32_t* posFlat = posKey + (size_t)NB * NFLAT;
    int* cnt2 = (int*)(posFlat + (size_t)NB * NFLAT);       // [640][P]
    uint2* cand2 = (uint2*)((char*)cnt2 + (size_t)NB * NCLS * P * 4); // [640][P][PCAP]

    (void)hipMemsetAsync(d_ws, 0, 4096, stream);

    cand_scan<<<NB * P, 256, 0, stream>>>(reinterpret_cast<const float4*>(pred),
                                          cand2, cnt2, oflow, cnt, P, CH);

    dim3 gb(NCLS, NB);
    nms_sel<<<gb, 256, 0, stream>>>(pred, cand2, cnt2, oflow, cnt, P,
                                    cls_boxes, posKey, posFlat, posCnt, dt);

    final_sel<<<NB, 256, 0, stream>>>(cls_boxes, posKey, posFlat, posCnt, out);
}

// Round 7
// 165.965 us; speedup vs baseline: 2.3715x; 2.3715x over previous
//
#include <hip/hip_runtime.h>
#include <math.h>
#include <stdint.h>

#define NANCH 49104
#define NCLS 80
#define KSEL 100
#define NFLAT (NCLS * KSEL)
#define PREDC 84
#define NB 8
#define ECAP 128
#define CAP 3072
#define BATF4 (NANCH * (PREDC / 4))        // 1,031,184 float4s per batch
#define BPB 64                              // cand_scan blocks per batch
#define LCAP 48                             // per-class LDS bucket cap
#define FASTN 1024                          // fast-select list cap
// logit(0.9): candidates are scores > 0.9; per-class top-100 threshold ~0.947 here
#define THRL 2.1972246f

struct DimsTable { float d[5][9][2]; };
struct KT { uint32_t key; int tie; };

__device__ __forceinline__ uint32_t f2key(float f) {
    uint32_t u = __float_as_uint(f);
    return u ^ (uint32_t((int32_t)u >> 31) | 0x80000000u);
}
__device__ __forceinline__ float key2f(uint32_t k) {
    uint32_t u = (k & 0x80000000u) ? (k ^ 0x80000000u) : ~k;
    return __uint_as_float(u);
}
__device__ __forceinline__ float sigm(float x) { return 1.0f / (1.0f + expf(-x)); }

__device__ __forceinline__ void decode_box(const float4 pv, int n,
                                           const DimsTable& dt, float box[4]) {
    int lev, base, fw, stride;
    if (n < 36864)      { lev = 0; base = 0;     fw = 64; stride = 8;   }
    else if (n < 46080) { lev = 1; base = 36864; fw = 32; stride = 16;  }
    else if (n < 48384) { lev = 2; base = 46080; fw = 16; stride = 32;  }
    else if (n < 48960) { lev = 3; base = 48384; fw = 8;  stride = 64;  }
    else                { lev = 4; base = 48960; fw = 4;  stride = 128; }
    int i = n - base;
    int k = i % 9;
    int cell = i / 9;
    int xq = cell % fw, yq = cell / fw;
    float cx = ((float)xq + 0.5f) * (float)stride;
    float cy = ((float)yq + 0.5f) * (float)stride;
    float aw = dt.d[lev][k][0];
    float ah = dt.d[lev][k][1];
    float tx = __fmul_rn(pv.x, 0.1f);
    float ty = __fmul_rn(pv.y, 0.1f);
    float tw = __fmul_rn(pv.z, 0.2f);
    float th = __fmul_rn(pv.w, 0.2f);
    float px = __fadd_rn(__fmul_rn(tx, aw), cx);
    float py = __fadd_rn(__fmul_rn(ty, ah), cy);
    float pw = __fmul_rn(expf(tw), aw);
    float ph = __fmul_rn(expf(th), ah);
    float hw = __fmul_rn(pw, 0.5f);
    float hh = __fmul_rn(ph, 0.5f);
    box[0] = __fsub_rn(px, hw);
    box[1] = __fsub_rn(py, hh);
    box[2] = __fadd_rn(px, hw);
    box[3] = __fadd_rn(py, hh);
}

struct alignas(16) SelSh {
    int hist[4][2048];        // 32 KB; overlaid as uint64 list64[FASTN] in fast path
    int suffix[256];
    uint32_t candKey[KSEL];
    int candIdx[KSEL];
    uint32_t eIdx[ECAP];
    uint32_t sKey[KSEL];
    int sIdx[KSEL];
    int cntG, cntE, krem, newkrem, digit, flast, rmin;
    uint32_t prefix, thrKey;
};

// Exact top-min(K,N) by (key desc, tie asc); fills sh.sKey/sIdx sorted. 256 thr.
template <typename G>
__device__ int block_select(G get, int N, int K, SelSh& sh) {
    const int tid = threadIdx.x;
    const int wid = tid >> 6;
    int Ksel = (N < K) ? N : K;
    if (Ksel <= 0) return 0;

    if (N <= K) {
        if (tid < N) { KT e = get(tid); sh.candKey[tid] = e.key; sh.candIdx[tid] = e.tie; }
        __syncthreads();
        if (tid < N) {
            uint32_t mk = sh.candKey[tid]; int mi = sh.candIdx[tid];
            int rank = 0;
            for (int j = 0; j < N; ++j) {
                uint32_t kj = sh.candKey[j]; int ij = sh.candIdx[j];
                rank += (kj > mk) || (kj == mk && ij < mi);
            }
            sh.sKey[rank] = mk; sh.sIdx[rank] = mi;
        }
        __syncthreads();
        return Ksel;
    }

    if (tid == 0) { sh.krem = K; sh.prefix = 0; }
    for (int pass = 0; pass < 3; ++pass) {
        const int bins   = (pass == 2) ? 1024 : 2048;
        const int dshift = (pass == 0) ? 21 : (pass == 1 ? 10 : 0);
        const int fshift = (pass == 1) ? 21 : 10;
        const int dmask  = bins - 1;
        const bool multi = (pass == 0);
        if (multi) { for (int j = tid; j < 4 * 2048; j += 256) ((int*)sh.hist)[j] = 0; }
        else       { for (int j = tid; j < bins; j += 256) sh.hist[0][j] = 0; }
        __syncthreads();
        const uint32_t pref = sh.prefix;
        for (int i = tid; i < N; i += 256) {
            uint32_t key = get(i).key;
            if (pass == 0) {
                atomicAdd(&sh.hist[wid][(key >> dshift) & dmask], 1);
            } else if ((key >> fshift) == pref) {
                atomicAdd(&sh.hist[0][(key >> dshift) & dmask], 1);
            }
        }
        __syncthreads();
        if (multi) {
            for (int j = tid; j < bins; j += 256)
                sh.hist[0][j] += sh.hist[1][j] + sh.hist[2][j] + sh.hist[3][j];
            __syncthreads();
        }
        const int cpb = bins / 256;
        const int base = tid * cpb;
        int lsum = 0;
        for (int j = 0; j < cpb; ++j) lsum += sh.hist[0][base + j];
        sh.suffix[tid] = lsum;
        __syncthreads();
        for (int off = 1; off < 256; off <<= 1) {
            int v = (tid + off < 256) ? sh.suffix[tid + off] : 0;
            __syncthreads();
            sh.suffix[tid] += v;
            __syncthreads();
        }
        {
            int cum = sh.suffix[tid] - lsum;
            const int krem = sh.krem;
            for (int j = cpb - 1; j >= 0; --j) {
                int cnt = sh.hist[0][base + j];
                if (cnt > 0 && cum < krem && cum + cnt >= krem) {
                    sh.digit = base + j;
                    sh.newkrem = krem - cum;
                }
                cum += cnt;
            }
        }
        __syncthreads();
        if (tid == 0) {
            sh.krem = sh.newkrem;
            if (pass == 0)      sh.prefix = (uint32_t)sh.digit;
            else if (pass == 1) sh.prefix = (sh.prefix << 11) | (uint32_t)sh.digit;
            else                sh.thrKey = (sh.prefix << 10) | (uint32_t)sh.digit;
        }
        __syncthreads();
    }

    if (tid == 0) { sh.cntG = 0; sh.cntE = 0; }
    __syncthreads();
    const uint32_t thr = sh.thrKey;
    for (int i = tid; i < N; i += 256) {
        KT e = get(i);
        if (e.key > thr) {
            int g = atomicAdd(&sh.cntG, 1);
            sh.candKey[g] = e.key; sh.candIdx[g] = e.tie;
        } else if (e.key == thr) {
            int idx = atomicAdd(&sh.cntE, 1);
            if (idx < ECAP) sh.eIdx[idx] = (uint32_t)e.tie;
        }
    }
    __syncthreads();
    const int need = sh.krem;
    const int nG = K - need;
    if (sh.cntE <= ECAP) {
        const int ce = sh.cntE;
        if (tid < ce) {
            uint32_t my = sh.eIdx[tid];
            int rank = 0;
            for (int j = 0; j < ce; ++j) rank += (sh.eIdx[j] < my);
            if (rank < need) { sh.candKey[nG + rank] = thr; sh.candIdx[nG + rank] = (int)my; }
        }
    } else {
        if (tid == 0) sh.flast = -1;
        __syncthreads();
        for (int t = 0; t < need; ++t) {
            if (tid == 0) sh.rmin = 0x7FFFFFFF;
            __syncthreads();
            const int fl = sh.flast;
            int lmin = 0x7FFFFFFF;
            for (int i = tid; i < N; i += 256) {
                KT e = get(i);
                if (e.key == thr && e.tie > fl) lmin = min(lmin, e.tie);
            }
            atomicMin(&sh.rmin, lmin);
            __syncthreads();
            if (tid == 0) { sh.candKey[nG + t] = thr; sh.candIdx[nG + t] = sh.rmin; sh.flast = sh.rmin; }
            __syncthreads();
        }
    }
    __syncthreads();
    if (tid < K) {
        uint32_t mk = sh.candKey[tid]; int mi = sh.candIdx[tid];
        int rank = 0;
        for (int j = 0; j < K; ++j) {
            uint32_t kj = sh.candKey[j]; int ij = sh.candIdx[j];
            rank += (kj > mk) || (kj == mk && ij < mi);
        }
        sh.sKey[rank] = mk; sh.sIdx[rank] = mi;
    }
    __syncthreads();
    return Ksel;
}

// ---------- kernel 1: coalesced scan + LDS buckets + bulk reservation --------
__device__ __forceinline__ void procf4(float4 p, int v, int b,
                                       int* lcnt, uint2 (*buck)[LCAP],
                                       int* cnt, uint2* cand) {
    uint32_t q = (uint32_t)v / 21u;
    uint32_t j = (uint32_t)v - q * 21u;
    if (j == 0u) return;
    bool c0 = p.x > THRL, c1 = p.y > THRL, c2 = p.z > THRL, c3 = p.w > THRL;
    if (!(c0 | c1 | c2 | c3)) return;
    uint32_t row = q - (uint32_t)b * (uint32_t)NANCH;
    int cbase = ((int)j - 1) * 4;
    float vv[4] = {p.x, p.y, p.z, p.w};
    bool pp[4] = {c0, c1, c2, c3};
#pragma unroll
    for (int k = 0; k < 4; ++k) {
        if (pp[k]) {
            int c = cbase + k;
            uint32_t key = f2key(sigm(vv[k]));
            int slot = atomicAdd(&lcnt[c], 1);
            if (slot < LCAP) {
                buck[c][slot] = make_uint2(key, row);
            } else {                       // rare: direct global reservation
                int bc = b * NCLS + c;
                int gs = atomicAdd(&cnt[bc], 1);
                if (gs < CAP) cand[(size_t)bc * CAP + gs] = make_uint2(key, row);
            }
        }
    }
}

__global__ __launch_bounds__(256) void cand_scan(const float4* __restrict__ predv,
                                                 uint2* __restrict__ cand,
                                                 int* __restrict__ cnt) {
    __shared__ uint2 buck[NCLS][LCAP];     // 30 KB
    __shared__ int lcnt[NCLS];
    __shared__ int gbase[NCLS];

    const int tid = threadIdx.x;
    const int b = blockIdx.x / BPB;
    const int part = blockIdx.x - b * BPB;
    const int CH = (BATF4 + BPB - 1) / BPB;

    for (int j = tid; j < NCLS; j += 256) lcnt[j] = 0;
    __syncthreads();

    int s = b * BATF4 + part * CH;
    int e = b * BATF4 + BATF4;
    if (s + CH < e) e = s + CH;

    int v = s + tid;
    for (; v + 768 < e; v += 1024) {       // 4 independent loads in flight
        float4 a0 = predv[v];
        float4 a1 = predv[v + 256];
        float4 a2 = predv[v + 512];
        float4 a3 = predv[v + 768];
        procf4(a0, v,       b, lcnt, buck, cnt, cand);
        procf4(a1, v + 256, b, lcnt, buck, cnt, cand);
        procf4(a2, v + 512, b, lcnt, buck, cnt, cand);
        procf4(a3, v + 768, b, lcnt, buck, cnt, cand);
    }
    for (; v < e; v += 256)
        procf4(predv[v], v, b, lcnt, buck, cnt, cand);
    __syncthreads();

    if (tid < NCLS) {
        int lc = lcnt[tid];
        if (lc > LCAP) lc = LCAP;
        gbase[tid] = (lc > 0) ? atomicAdd(&cnt[b * NCLS + tid], lc) : 0;
    }
    __syncthreads();

    for (int x = tid; x < NCLS * LCAP; x += 256) {
        int c = x / LCAP;
        int k = x - c * LCAP;
        int lc = lcnt[c];
        if (lc > LCAP) lc = LCAP;
        if (k < lc) {
            int gs = gbase[c] + k;
            if (gs < CAP)
                cand[(size_t)(b * NCLS + c) * CAP + gs] = buck[c][k];
        }
    }
}

// ---------- kernel 2: coalesced gather + streaming rank-select + wave NMS ----
__global__ __launch_bounds__(256) void nms_sel(const float* __restrict__ pred,
                                               const uint2* __restrict__ cand,
                                               const int* __restrict__ cnt,
                                               float* __restrict__ cls_boxes,
                                               uint32_t* __restrict__ posKey,
                                               uint32_t* __restrict__ posFlat,
                                               int* __restrict__ posCnt,
                                               DimsTable dt) {
    __shared__ SelSh sh;
    const int c = blockIdx.x;
    const int b = blockIdx.y;
    const int tid = threadIdx.x;
    const int bc = b * NCLS + c;
    const int n = cnt[bc];

    if (n >= KSEL && n <= FASTN) {
        // pack (key desc, row asc) into one descending uint64 key
        unsigned long long* list64 = (unsigned long long*)sh.hist;  // 8 KB used
        const uint2* src = cand + (size_t)bc * CAP;
        for (int x = tid; x < n; x += 256) {
            uint2 p = src[x];                                  // coalesced
            list64[x] = ((unsigned long long)p.x << 32) |
                        (unsigned long long)(~p.y);
        }
        __syncthreads();
        unsigned long long e0 = 0, e1 = 0, e2 = 0, e3 = 0;
        const bool v0 = tid < n, v1 = tid + 256 < n, v2 = tid + 512 < n, v3 = tid + 768 < n;
        if (v0) e0 = list64[tid];
        if (v1) e1 = list64[tid + 256];
        if (v2) e2 = list64[tid + 512];
        if (v3) e3 = list64[tid + 768];
        int r0 = 0, r1 = 0, r2 = 0, r3 = 0;
        int j = 0;
        for (; j + 3 < n; j += 4) {                            // 4 reads in flight
            unsigned long long o0 = list64[j];
            unsigned long long o1 = list64[j + 1];
            unsigned long long o2 = list64[j + 2];
            unsigned long long o3 = list64[j + 3];
            r0 += (o0 > e0) + (o1 > e0) + (o2 > e0) + (o3 > e0);
            r1 += (o0 > e1) + (o1 > e1) + (o2 > e1) + (o3 > e1);
            r2 += (o0 > e2) + (o1 > e2) + (o2 > e2) + (o3 > e2);
            r3 += (o0 > e3) + (o1 > e3) + (o2 > e3) + (o3 > e3);
        }
        for (; j < n; ++j) {
            unsigned long long o = list64[j];
            r0 += (o > e0); r1 += (o > e1); r2 += (o > e2); r3 += (o > e3);
        }
        if (v0 && r0 < KSEL) { sh.sKey[r0] = (uint32_t)(e0 >> 32); sh.sIdx[r0] = (int)(~(uint32_t)e0); }
        if (v1 && r1 < KSEL) { sh.sKey[r1] = (uint32_t)(e1 >> 32); sh.sIdx[r1] = (int)(~(uint32_t)e1); }
        if (v2 && r2 < KSEL) { sh.sKey[r2] = (uint32_t)(e2 >> 32); sh.sIdx[r2] = (int)(~(uint32_t)e2); }
        if (v3 && r3 < KSEL) { sh.sKey[r3] = (uint32_t)(e3 >> 32); sh.sIdx[r3] = (int)(~(uint32_t)e3); }
        __syncthreads();
    } else {
        // exact fallback: full strided scan (never taken on this data)
        const float* src = pred + (size_t)b * NANCH * PREDC + 4 + c;
        auto g = [src](int i) { KT e; e.key = f2key(sigm(src[(size_t)i * PREDC])); e.tie = i; return e; };
        block_select(g, NANCH, KSEL, sh);
    }

    if (tid < 64) {
        const int l = tid;
        uint32_t key0 = sh.sKey[l]; int n0i = sh.sIdx[l];
        float4 pv0 = reinterpret_cast<const float4*>(pred)[((size_t)b * NANCH + n0i) * (PREDC / 4) + 0];
        float b0[4]; decode_box(pv0, n0i, dt, b0);
        float area0 = __fmul_rn(__fsub_rn(b0[2], b0[0]), __fsub_rn(b0[3], b0[1]));
        int k0 = key2f(key0) > 0.05f;

        const bool has1 = (l + 64) < KSEL;
        uint32_t key1 = 0; int n1i = 0;
        float b1[4] = {0.f, 0.f, 0.f, 0.f}; float area1 = 0.f; int k1 = 0;
        if (has1) {
            key1 = sh.sKey[l + 64]; n1i = sh.sIdx[l + 64];
            float4 pv1 = reinterpret_cast<const float4*>(pred)[((size_t)b * NANCH + n1i) * (PREDC / 4) + 0];
            decode_box(pv1, n1i, dt, b1);
            area1 = __fmul_rn(__fsub_rn(b1[2], b1[0]), __fsub_rn(b1[3], b1[1]));
            k1 = key2f(key1) > 0.05f;
        }

        for (int i = 0; i < KSEL; ++i) {
            int kk; float c0, c1, c2, c3, ca;
            if (i < 64) { kk = k0; c0 = b0[0]; c1 = b0[1]; c2 = b0[2]; c3 = b0[3]; ca = area0; }
            else        { kk = k1; c0 = b1[0]; c1 = b1[1]; c2 = b1[2]; c3 = b1[3]; ca = area1; }
            const int sl = i & 63;
            int ki = __shfl(kk, sl);
            if (ki) {
                float ix0 = __shfl(c0, sl), iy0 = __shfl(c1, sl);
                float ix1 = __shfl(c2, sl), iy1 = __shfl(c3, sl);
                float ia  = __shfl(ca, sl);
                if (k0 && l > i) {
                    float x1 = fmaxf(ix0, b0[0]), y1 = fmaxf(iy0, b0[1]);
                    float x2 = fminf(ix1, b0[2]), y2 = fminf(iy1, b0[3]);
                    float iw = fmaxf(__fsub_rn(x2, x1), 0.0f);
                    float ih = fmaxf(__fsub_rn(y2, y1), 0.0f);
                    float inter = __fmul_rn(iw, ih);
                    float uni = __fsub_rn(__fadd_rn(ia, area0), inter);
                    if (__fdiv_rn(inter, fmaxf(uni, 1e-8f)) > 0.5f) k0 = 0;
                }
                if (k1 && (l + 64) > i) {
                    float x1 = fmaxf(ix0, b1[0]), y1 = fmaxf(iy0, b1[1]);
                    float x2 = fminf(ix1, b1[2]), y2 = fminf(iy1, b1[3]);
                    float iw = fmaxf(__fsub_rn(x2, x1), 0.0f);
                    float ih = fmaxf(__fsub_rn(y2, y1), 0.0f);
                    float inter = __fmul_rn(iw, ih);
                    float uni = __fsub_rn(__fadd_rn(ia, area1), inter);
                    if (__fdiv_rn(inter, fmaxf(uni, 1e-8f)) > 0.5f) k1 = 0;
                }
            }
        }

        reinterpret_cast<float4*>(cls_boxes)[(size_t)b * NFLAT + c * KSEL + l] =
            make_float4(b0[0], b0[1], b0[2], b0[3]);
        if (has1)
            reinterpret_cast<float4*>(cls_boxes)[(size_t)b * NFLAT + c * KSEL + l + 64] =
                make_float4(b1[0], b1[1], b1[2], b1[3]);

        unsigned long long m0 = __ballot(k0);
        unsigned long long m1 = __ballot(k1);
        int tot = __popcll(m0) + __popcll(m1);
        int base;
        if (l == 0) base = atomicAdd(&posCnt[b], tot);
        base = __shfl(base, 0);
        if (k0) {
            int off = __popcll(m0 & ((1ull << l) - 1));
            posKey[(size_t)b * NFLAT + base + off] = key0;
            posFlat[(size_t)b * NFLAT + base + off] = (uint32_t)(c * KSEL + l);
        }
        if (k1) {
            int off = __popcll(m0) + __popcll(m1 & ((1ull << l) - 1));
            posKey[(size_t)b * NFLAT + base + off] = key1;
            posFlat[(size_t)b * NFLAT + base + off] = (uint32_t)(c * KSEL + l + 64);
        }
    }
}

// ---------- kernel 3: per-batch final top-100 over compacted positives -------
__global__ __launch_bounds__(256) void final_sel(const float* __restrict__ cls_boxes,
                                                 const uint32_t* __restrict__ posKey,
                                                 const uint32_t* __restrict__ posFlat,
                                                 const int* __restrict__ posCnt,
                                                 float* __restrict__ out) {
    __shared__ SelSh sh;
    const int b = blockIdx.x;
    const int tid = threadIdx.x;
    int m = posCnt[b];
    if (m > NFLAT) m = NFLAT;
    const uint32_t* pk = posKey + (size_t)b * NFLAT;
    const uint32_t* pf = posFlat + (size_t)b * NFLAT;
    auto g = [pk, pf](int i) { KT e; e.key = pk[i]; e.tie = (int)pf[i]; return e; };
    int K = block_select(g, m, KSEL, sh);
    if (tid < KSEL) {
        float4 ob = make_float4(0.f, 0.f, 0.f, 0.f);
        float sv = 0.f, cv = 0.f;
        if (tid < K) {
            sv = key2f(sh.sKey[tid]);
            int flat = sh.sIdx[tid];
            ob = reinterpret_cast<const float4*>(cls_boxes)[(size_t)b * NFLAT + flat];
            cv = (float)(flat / KSEL);
        }
        reinterpret_cast<float4*>(out)[(size_t)b * KSEL + tid] = ob;
        out[NB * KSEL * 4 + b * KSEL + tid] = sv;
        out[NB * KSEL * 5 + b * KSEL + tid] = cv;
    }
    if (tid == 0) out[NB * KSEL * 6 + b] = (float)K;
}

// ---------- host launcher ----------------------------------------------------
extern "C" void kernel_launch(void* const* d_in, const int* in_sizes, int n_in,
                              void* d_out, int out_size, void* d_ws, size_t ws_size,
                              hipStream_t stream) {
    const float* pred = (const float*)d_in[1];
    float* out = (float*)d_out;

    DimsTable dt;
    const double areasd[5] = {1024.0, 4096.0, 16384.0, 65536.0, 262144.0};
    const double ratios[3] = {0.5, 1.0, 2.0};
    const double scales[3] = {1.0, pow(2.0, 1.0 / 3.0), pow(2.0, 2.0 / 3.0)};
    for (int l = 0; l < 5; ++l)
        for (int ri = 0; ri < 3; ++ri) {
            double ah = sqrt(areasd[l] / ratios[ri]);
            double aw = areasd[l] / ah;
            for (int si = 0; si < 3; ++si) {
                dt.d[l][ri * 3 + si][0] = (float)(aw * scales[si]);
                dt.d[l][ri * 3 + si][1] = (float)(ah * scales[si]);
            }
        }

    // workspace layout (round-5 proven): ~17.3 MB
    char* wsb = (char*)d_ws;
    int* cnt = (int*)wsb;                       // [640]
    int* posCnt = cnt + NB * NCLS;              // [8]
    uint2* cand = (uint2*)(wsb + 4096);         // [640][CAP]
    float* cls_boxes = (float*)((char*)cand + (size_t)NB * NCLS * CAP * 8);  // [8][8000][4]
    uint32_t* posKey = (uint32_t*)(cls_boxes + (size_t)NB * NFLAT * 4);      // [8][8000]
    uint32_t* posFlat = posKey + (size_t)NB * NFLAT;                          // [8][8000]

    (void)hipMemsetAsync(d_ws, 0, 4096, stream);

    cand_scan<<<NB * BPB, 256, 0, stream>>>(reinterpret_cast<const float4*>(pred),
                                            cand, cnt);

    dim3 gb(NCLS, NB);
    nms_sel<<<gb, 256, 0, stream>>>(pred, cand, cnt, cls_boxes, posKey, posFlat,
                                    posCnt, dt);

    final_sel<<<NB, 256, 0, stream>>>(cls_boxes, posKey, posFlat, posCnt, out);
}

// Round 8
// 160.926 us; speedup vs baseline: 2.4457x; 1.0313x over previous
//
#include <hip/hip_runtime.h>
#include <math.h>
#include <stdint.h>

#define NANCH 49104
#define NCLS 80
#define KSEL 100
#define NFLAT (NCLS * KSEL)
#define PREDC 84
#define NB 8
#define ECAP 128
#define CAP 3072
#define BATF4 (NANCH * (PREDC / 4))        // 1,031,184 float4s per batch
#define BPB 96                              // cand_scan blocks per batch
#define LCAP 32                             // per-class LDS bucket cap
#define FASTN 1024                          // fast-select list cap
// logit(0.9): candidates are scores > 0.9; per-class top-100 threshold ~0.947 here
#define THRL 2.1972246f

struct DimsTable { float d[5][9][2]; };
struct KT { uint32_t key; int tie; };

__device__ __forceinline__ uint32_t f2key(float f) {
    uint32_t u = __float_as_uint(f);
    return u ^ (uint32_t((int32_t)u >> 31) | 0x80000000u);
}
__device__ __forceinline__ float key2f(uint32_t k) {
    uint32_t u = (k & 0x80000000u) ? (k ^ 0x80000000u) : ~k;
    return __uint_as_float(u);
}
__device__ __forceinline__ float sigm(float x) { return 1.0f / (1.0f + expf(-x)); }

__device__ __forceinline__ void decode_box(const float4 pv, int n,
                                           const DimsTable& dt, float box[4]) {
    int lev, base, fw, stride;
    if (n < 36864)      { lev = 0; base = 0;     fw = 64; stride = 8;   }
    else if (n < 46080) { lev = 1; base = 36864; fw = 32; stride = 16;  }
    else if (n < 48384) { lev = 2; base = 46080; fw = 16; stride = 32;  }
    else if (n < 48960) { lev = 3; base = 48384; fw = 8;  stride = 64;  }
    else                { lev = 4; base = 48960; fw = 4;  stride = 128; }
    int i = n - base;
    int k = i % 9;
    int cell = i / 9;
    int xq = cell % fw, yq = cell / fw;
    float cx = ((float)xq + 0.5f) * (float)stride;
    float cy = ((float)yq + 0.5f) * (float)stride;
    float aw = dt.d[lev][k][0];
    float ah = dt.d[lev][k][1];
    float tx = __fmul_rn(pv.x, 0.1f);
    float ty = __fmul_rn(pv.y, 0.1f);
    float tw = __fmul_rn(pv.z, 0.2f);
    float th = __fmul_rn(pv.w, 0.2f);
    float px = __fadd_rn(__fmul_rn(tx, aw), cx);
    float py = __fadd_rn(__fmul_rn(ty, ah), cy);
    float pw = __fmul_rn(expf(tw), aw);
    float ph = __fmul_rn(expf(th), ah);
    float hw = __fmul_rn(pw, 0.5f);
    float hh = __fmul_rn(ph, 0.5f);
    box[0] = __fsub_rn(px, hw);
    box[1] = __fsub_rn(py, hh);
    box[2] = __fadd_rn(px, hw);
    box[3] = __fadd_rn(py, hh);
}

struct alignas(16) SelSh {
    int hist[4][2048];        // 32 KB; overlaid as uint64 list64[FASTN] in fast path
    int suffix[256];
    uint32_t candKey[KSEL];
    int candIdx[KSEL];
    uint32_t eIdx[ECAP];
    uint32_t sKey[KSEL];
    int sIdx[KSEL];
    int cntG, cntE, krem, newkrem, digit, flast, rmin;
    uint32_t prefix, thrKey;
};

// Exact top-min(K,N) by (key desc, tie asc); fills sh.sKey/sIdx sorted. 256 thr.
template <typename G>
__device__ int block_select(G get, int N, int K, SelSh& sh) {
    const int tid = threadIdx.x;
    const int wid = tid >> 6;
    int Ksel = (N < K) ? N : K;
    if (Ksel <= 0) return 0;

    if (N <= K) {
        if (tid < N) { KT e = get(tid); sh.candKey[tid] = e.key; sh.candIdx[tid] = e.tie; }
        __syncthreads();
        if (tid < N) {
            uint32_t mk = sh.candKey[tid]; int mi = sh.candIdx[tid];
            int rank = 0;
            for (int j = 0; j < N; ++j) {
                uint32_t kj = sh.candKey[j]; int ij = sh.candIdx[j];
                rank += (kj > mk) || (kj == mk && ij < mi);
            }
            sh.sKey[rank] = mk; sh.sIdx[rank] = mi;
        }
        __syncthreads();
        return Ksel;
    }

    if (tid == 0) { sh.krem = K; sh.prefix = 0; }
    for (int pass = 0; pass < 3; ++pass) {
        const int bins   = (pass == 2) ? 1024 : 2048;
        const int dshift = (pass == 0) ? 21 : (pass == 1 ? 10 : 0);
        const int fshift = (pass == 1) ? 21 : 10;
        const int dmask  = bins - 1;
        const bool multi = (pass == 0);
        if (multi) { for (int j = tid; j < 4 * 2048; j += 256) ((int*)sh.hist)[j] = 0; }
        else       { for (int j = tid; j < bins; j += 256) sh.hist[0][j] = 0; }
        __syncthreads();
        const uint32_t pref = sh.prefix;
        for (int i = tid; i < N; i += 256) {
            uint32_t key = get(i).key;
            if (pass == 0) {
                atomicAdd(&sh.hist[wid][(key >> dshift) & dmask], 1);
            } else if ((key >> fshift) == pref) {
                atomicAdd(&sh.hist[0][(key >> dshift) & dmask], 1);
            }
        }
        __syncthreads();
        if (multi) {
            for (int j = tid; j < bins; j += 256)
                sh.hist[0][j] += sh.hist[1][j] + sh.hist[2][j] + sh.hist[3][j];
            __syncthreads();
        }
        const int cpb = bins / 256;
        const int base = tid * cpb;
        int lsum = 0;
        for (int j = 0; j < cpb; ++j) lsum += sh.hist[0][base + j];
        sh.suffix[tid] = lsum;
        __syncthreads();
        for (int off = 1; off < 256; off <<= 1) {
            int v = (tid + off < 256) ? sh.suffix[tid + off] : 0;
            __syncthreads();
            sh.suffix[tid] += v;
            __syncthreads();
        }
        {
            int cum = sh.suffix[tid] - lsum;
            const int krem = sh.krem;
            for (int j = cpb - 1; j >= 0; --j) {
                int cnt = sh.hist[0][base + j];
                if (cnt > 0 && cum < krem && cum + cnt >= krem) {
                    sh.digit = base + j;
                    sh.newkrem = krem - cum;
                }
                cum += cnt;
            }
        }
        __syncthreads();
        if (tid == 0) {
            sh.krem = sh.newkrem;
            if (pass == 0)      sh.prefix = (uint32_t)sh.digit;
            else if (pass == 1) sh.prefix = (sh.prefix << 11) | (uint32_t)sh.digit;
            else                sh.thrKey = (sh.prefix << 10) | (uint32_t)sh.digit;
        }
        __syncthreads();
    }

    if (tid == 0) { sh.cntG = 0; sh.cntE = 0; }
    __syncthreads();
    const uint32_t thr = sh.thrKey;
    for (int i = tid; i < N; i += 256) {
        KT e = get(i);
        if (e.key > thr) {
            int g = atomicAdd(&sh.cntG, 1);
            sh.candKey[g] = e.key; sh.candIdx[g] = e.tie;
        } else if (e.key == thr) {
            int idx = atomicAdd(&sh.cntE, 1);
            if (idx < ECAP) sh.eIdx[idx] = (uint32_t)e.tie;
        }
    }
    __syncthreads();
    const int need = sh.krem;
    const int nG = K - need;
    if (sh.cntE <= ECAP) {
        const int ce = sh.cntE;
        if (tid < ce) {
            uint32_t my = sh.eIdx[tid];
            int rank = 0;
            for (int j = 0; j < ce; ++j) rank += (sh.eIdx[j] < my);
            if (rank < need) { sh.candKey[nG + rank] = thr; sh.candIdx[nG + rank] = (int)my; }
        }
    } else {
        if (tid == 0) sh.flast = -1;
        __syncthreads();
        for (int t = 0; t < need; ++t) {
            if (tid == 0) sh.rmin = 0x7FFFFFFF;
            __syncthreads();
            const int fl = sh.flast;
            int lmin = 0x7FFFFFFF;
            for (int i = tid; i < N; i += 256) {
                KT e = get(i);
                if (e.key == thr && e.tie > fl) lmin = min(lmin, e.tie);
            }
            atomicMin(&sh.rmin, lmin);
            __syncthreads();
            if (tid == 0) { sh.candKey[nG + t] = thr; sh.candIdx[nG + t] = sh.rmin; sh.flast = sh.rmin; }
            __syncthreads();
        }
    }
    __syncthreads();
    if (tid < K) {
        uint32_t mk = sh.candKey[tid]; int mi = sh.candIdx[tid];
        int rank = 0;
        for (int j = 0; j < K; ++j) {
            uint32_t kj = sh.candKey[j]; int ij = sh.candIdx[j];
            rank += (kj > mk) || (kj == mk && ij < mi);
        }
        sh.sKey[rank] = mk; sh.sIdx[rank] = mi;
    }
    __syncthreads();
    return Ksel;
}

// ---------- kernel 0: zero counters -----------------------------------------
__global__ __launch_bounds__(256) void init_k(int* __restrict__ cnt) {
    for (int x = threadIdx.x; x < NB * NCLS + NB; x += 256) cnt[x] = 0;
}

// ---------- kernel 1: coalesced scan + LDS buckets + bulk reservation --------
__device__ __forceinline__ void procf4(float4 p, int v, int b,
                                       int* lcnt, uint2 (*buck)[LCAP],
                                       int* cnt, uint2* cand) {
    uint32_t q = (uint32_t)v / 21u;
    uint32_t j = (uint32_t)v - q * 21u;
    if (j == 0u) return;
    bool c0 = p.x > THRL, c1 = p.y > THRL, c2 = p.z > THRL, c3 = p.w > THRL;
    if (!(c0 | c1 | c2 | c3)) return;
    uint32_t row = q - (uint32_t)b * (uint32_t)NANCH;
    int cbase = ((int)j - 1) * 4;
    float vv[4] = {p.x, p.y, p.z, p.w};
    bool pp[4] = {c0, c1, c2, c3};
#pragma unroll
    for (int k = 0; k < 4; ++k) {
        if (pp[k]) {
            int c = cbase + k;
            uint32_t key = f2key(sigm(vv[k]));
            int slot = atomicAdd(&lcnt[c], 1);
            if (slot < LCAP) {
                buck[c][slot] = make_uint2(key, row);
            } else {                       // rare: direct global reservation
                int bc = b * NCLS + c;
                int gs = atomicAdd(&cnt[bc], 1);
                if (gs < CAP) cand[(size_t)bc * CAP + gs] = make_uint2(key, row);
            }
        }
    }
}

__global__ __launch_bounds__(256) void cand_scan(const float4* __restrict__ predv,
                                                 uint2* __restrict__ cand,
                                                 int* __restrict__ cnt) {
    __shared__ uint2 buck[NCLS][LCAP];     // 20 KB
    __shared__ int lcnt[NCLS];
    __shared__ int gbase[NCLS];

    const int tid = threadIdx.x;
    const int b = blockIdx.x / BPB;
    const int part = blockIdx.x - b * BPB;
    const int CH = (BATF4 + BPB - 1) / BPB;

    for (int j = tid; j < NCLS; j += 256) lcnt[j] = 0;
    __syncthreads();

    int s = b * BATF4 + part * CH;
    int e = b * BATF4 + BATF4;
    if (s + CH < e) e = s + CH;

    int v = s + tid;
    for (; v + 768 < e; v += 1024) {       // 4 independent loads in flight
        float4 a0 = predv[v];
        float4 a1 = predv[v + 256];
        float4 a2 = predv[v + 512];
        float4 a3 = predv[v + 768];
        procf4(a0, v,       b, lcnt, buck, cnt, cand);
        procf4(a1, v + 256, b, lcnt, buck, cnt, cand);
        procf4(a2, v + 512, b, lcnt, buck, cnt, cand);
        procf4(a3, v + 768, b, lcnt, buck, cnt, cand);
    }
    for (; v < e; v += 256)
        procf4(predv[v], v, b, lcnt, buck, cnt, cand);
    __syncthreads();

    if (tid < NCLS) {
        int lc = lcnt[tid];
        if (lc > LCAP) lc = LCAP;
        gbase[tid] = (lc > 0) ? atomicAdd(&cnt[b * NCLS + tid], lc) : 0;
    }
    __syncthreads();

    for (int x = tid; x < NCLS * LCAP; x += 256) {
        int c = x >> 5;                    // LCAP = 32
        int k = x & (LCAP - 1);
        int lc = lcnt[c];
        if (lc > LCAP) lc = LCAP;
        if (k < lc) {
            int gs = gbase[c] + k;
            if (gs < CAP)
                cand[(size_t)(b * NCLS + c) * CAP + gs] = buck[c][k];
        }
    }
}

// ---------- kernel 2: rank-select top-100 + parallel-IoU NMS -----------------
__global__ __launch_bounds__(256) void nms_sel(const float* __restrict__ pred,
                                               const uint2* __restrict__ cand,
                                               const int* __restrict__ cnt,
                                               float* __restrict__ cls_boxes,
                                               uint32_t* __restrict__ posKey,
                                               uint32_t* __restrict__ posFlat,
                                               int* __restrict__ posCnt,
                                               DimsTable dt) {
    __shared__ SelSh sh;
    __shared__ float sbox[KSEL][4];
    __shared__ float sarea[KSEL];
    __shared__ int sconf[KSEL];
    __shared__ uint32_t sup[KSEL][4];
    __shared__ uint32_t keepm[4];
    __shared__ int baseSh;
    const int c = blockIdx.x;
    const int b = blockIdx.y;
    const int tid = threadIdx.x;
    const int bc = b * NCLS + c;
    const int n = cnt[bc];

    if (n >= KSEL && n <= FASTN) {
        // pack (key desc, row asc) into one descending uint64 key
        unsigned long long* list64 = (unsigned long long*)sh.hist;  // 8 KB used
        const uint2* src = cand + (size_t)bc * CAP;
        for (int x = tid; x < n; x += 256) {
            uint2 p = src[x];                                  // coalesced
            list64[x] = ((unsigned long long)p.x << 32) |
                        (unsigned long long)(~p.y);
        }
        __syncthreads();
        unsigned long long e0 = 0, e1 = 0, e2 = 0, e3 = 0;
        const bool v0 = tid < n, v1 = tid + 256 < n, v2 = tid + 512 < n, v3 = tid + 768 < n;
        if (v0) e0 = list64[tid];
        if (v1) e1 = list64[tid + 256];
        if (v2) e2 = list64[tid + 512];
        if (v3) e3 = list64[tid + 768];
        int r0 = 0, r1 = 0, r2 = 0, r3 = 0;
        const ulonglong2* l2 = (const ulonglong2*)list64;
        int j = 0;
        for (; j + 7 < n; j += 8) {                           // 4 b128 reads in flight
            ulonglong2 q0 = l2[(j >> 1) + 0];
            ulonglong2 q1 = l2[(j >> 1) + 1];
            ulonglong2 q2 = l2[(j >> 1) + 2];
            ulonglong2 q3 = l2[(j >> 1) + 3];
            r0 += (q0.x > e0) + (q0.y > e0) + (q1.x > e0) + (q1.y > e0)
                + (q2.x > e0) + (q2.y > e0) + (q3.x > e0) + (q3.y > e0);
            r1 += (q0.x > e1) + (q0.y > e1) + (q1.x > e1) + (q1.y > e1)
                + (q2.x > e1) + (q2.y > e1) + (q3.x > e1) + (q3.y > e1);
            r2 += (q0.x > e2) + (q0.y > e2) + (q1.x > e2) + (q1.y > e2)
                + (q2.x > e2) + (q2.y > e2) + (q3.x > e2) + (q3.y > e2);
            r3 += (q0.x > e3) + (q0.y > e3) + (q1.x > e3) + (q1.y > e3)
                + (q2.x > e3) + (q2.y > e3) + (q3.x > e3) + (q3.y > e3);
        }
        for (; j < n; ++j) {
            unsigned long long o = list64[j];
            r0 += (o > e0); r1 += (o > e1); r2 += (o > e2); r3 += (o > e3);
        }
        if (v0 && r0 < KSEL) { sh.sKey[r0] = (uint32_t)(e0 >> 32); sh.sIdx[r0] = (int)(~(uint32_t)e0); }
        if (v1 && r1 < KSEL) { sh.sKey[r1] = (uint32_t)(e1 >> 32); sh.sIdx[r1] = (int)(~(uint32_t)e1); }
        if (v2 && r2 < KSEL) { sh.sKey[r2] = (uint32_t)(e2 >> 32); sh.sIdx[r2] = (int)(~(uint32_t)e2); }
        if (v3 && r3 < KSEL) { sh.sKey[r3] = (uint32_t)(e3 >> 32); sh.sIdx[r3] = (int)(~(uint32_t)e3); }
        __syncthreads();
    } else {
        // exact fallback: full strided scan (never taken on this data)
        const float* src = pred + (size_t)b * NANCH * PREDC + 4 + c;
        auto g = [src](int i) { KT e; e.key = f2key(sigm(src[(size_t)i * PREDC])); e.tie = i; return e; };
        block_select(g, NANCH, KSEL, sh);
    }

    // ---- decode the 100 boxes + conf flags (parallel) ----
    for (int x = tid; x < KSEL * 4; x += 256) ((uint32_t*)sup)[x] = 0;
    if (tid < KSEL) {
        int ni = sh.sIdx[tid];
        float4 pv = reinterpret_cast<const float4*>(pred)[((size_t)b * NANCH + ni) * (PREDC / 4)];
        float bx[4]; decode_box(pv, ni, dt, bx);
        sbox[tid][0] = bx[0]; sbox[tid][1] = bx[1];
        sbox[tid][2] = bx[2]; sbox[tid][3] = bx[3];
        sarea[tid] = __fmul_rn(__fsub_rn(bx[2], bx[0]), __fsub_rn(bx[3], bx[1]));
        sconf[tid] = (key2f(sh.sKey[tid]) > 0.05f) ? 1 : 0;
    }
    __syncthreads();

    // ---- parallel IoU suppression matrix (j > i bits only) ----
    for (int pidx = tid; pidx < KSEL * KSEL; pidx += 256) {
        int i = pidx / KSEL;
        int jj = pidx - i * KSEL;
        if (jj > i && sconf[i] && sconf[jj]) {
            float x1 = fmaxf(sbox[i][0], sbox[jj][0]);
            float y1 = fmaxf(sbox[i][1], sbox[jj][1]);
            float x2 = fminf(sbox[i][2], sbox[jj][2]);
            float y2 = fminf(sbox[i][3], sbox[jj][3]);
            float iw = fmaxf(__fsub_rn(x2, x1), 0.0f);
            float ih = fmaxf(__fsub_rn(y2, y1), 0.0f);
            float inter = __fmul_rn(iw, ih);
            float uni = __fsub_rn(__fadd_rn(sarea[i], sarea[jj]), inter);
            if (__fdiv_rn(inter, fmaxf(uni, 1e-8f)) > 0.5f)
                atomicOr(&sup[i][jj >> 5], 1u << (jj & 31));
        }
    }
    __syncthreads();

    // ---- greedy pass over the bitmask (single thread, registers) ----
    if (tid == 0) {
        uint32_t k0 = 0, k1 = 0, k2 = 0, k3 = 0;
        for (int i = 0; i < KSEL; ++i)
            if (sconf[i]) { if (i < 32) k0 |= 1u << i; else if (i < 64) k1 |= 1u << (i - 32);
                            else if (i < 96) k2 |= 1u << (i - 64); else k3 |= 1u << (i - 96); }
        for (int i = 0; i < KSEL; ++i) {
            uint32_t w = (i < 32) ? k0 : (i < 64) ? k1 : (i < 96) ? k2 : k3;
            if ((w >> (i & 31)) & 1u) {
                k0 &= ~sup[i][0]; k1 &= ~sup[i][1]; k2 &= ~sup[i][2]; k3 &= ~sup[i][3];
            }
        }
        keepm[0] = k0; keepm[1] = k1; keepm[2] = k2; keepm[3] = k3;
        baseSh = atomicAdd(&posCnt[b],
                           __popc(k0) + __popc(k1) + __popc(k2) + __popc(k3));
    }
    __syncthreads();

    // ---- write boxes + append kept positives ----
    if (tid < KSEL) {
        reinterpret_cast<float4*>(cls_boxes)[(size_t)b * NFLAT + c * KSEL + tid] =
            make_float4(sbox[tid][0], sbox[tid][1], sbox[tid][2], sbox[tid][3]);
        int w = tid >> 5, bit = tid & 31;
        if ((keepm[w] >> bit) & 1u) {
            int off = __popc(keepm[w] & ((bit == 0) ? 0u : ((1u << bit) - 1u)));
            for (int ww = 0; ww < w; ++ww) off += __popc(keepm[ww]);
            posKey[(size_t)b * NFLAT + baseSh + off] = sh.sKey[tid];
            posFlat[(size_t)b * NFLAT + baseSh + off] = (uint32_t)(c * KSEL + tid);
        }
    }
}

// ---------- kernel 3: per-batch final top-100 over compacted positives -------
__global__ __launch_bounds__(256) void final_sel(const float* __restrict__ cls_boxes,
                                                 const uint32_t* __restrict__ posKey,
                                                 const uint32_t* __restrict__ posFlat,
                                                 const int* __restrict__ posCnt,
                                                 float* __restrict__ out) {
    __shared__ SelSh sh;
    const int b = blockIdx.x;
    const int tid = threadIdx.x;
    int m = posCnt[b];
    if (m > NFLAT) m = NFLAT;
    const uint32_t* pk = posKey + (size_t)b * NFLAT;
    const uint32_t* pf = posFlat + (size_t)b * NFLAT;
    auto g = [pk, pf](int i) { KT e; e.key = pk[i]; e.tie = (int)pf[i]; return e; };
    int K = block_select(g, m, KSEL, sh);
    if (tid < KSEL) {
        float4 ob = make_float4(0.f, 0.f, 0.f, 0.f);
        float sv = 0.f, cv = 0.f;
        if (tid < K) {
            sv = key2f(sh.sKey[tid]);
            int flat = sh.sIdx[tid];
            ob = reinterpret_cast<const float4*>(cls_boxes)[(size_t)b * NFLAT + flat];
            cv = (float)(flat / KSEL);
        }
        reinterpret_cast<float4*>(out)[(size_t)b * KSEL + tid] = ob;
        out[NB * KSEL * 4 + b * KSEL + tid] = sv;
        out[NB * KSEL * 5 + b * KSEL + tid] = cv;
    }
    if (tid == 0) out[NB * KSEL * 6 + b] = (float)K;
}

// ---------- host launcher ----------------------------------------------------
extern "C" void kernel_launch(void* const* d_in, const int* in_sizes, int n_in,
                              void* d_out, int out_size, void* d_ws, size_t ws_size,
                              hipStream_t stream) {
    const float* pred = (const float*)d_in[1];
    float* out = (float*)d_out;

    DimsTable dt;
    const double areasd[5] = {1024.0, 4096.0, 16384.0, 65536.0, 262144.0};
    const double ratios[3] = {0.5, 1.0, 2.0};
    const double scales[3] = {1.0, pow(2.0, 1.0 / 3.0), pow(2.0, 2.0 / 3.0)};
    for (int l = 0; l < 5; ++l)
        for (int ri = 0; ri < 3; ++ri) {
            double ah = sqrt(areasd[l] / ratios[ri]);
            double aw = areasd[l] / ah;
            for (int si = 0; si < 3; ++si) {
                dt.d[l][ri * 3 + si][0] = (float)(aw * scales[si]);
                dt.d[l][ri * 3 + si][1] = (float)(ah * scales[si]);
            }
        }

    // workspace layout: ~17.3 MB
    char* wsb = (char*)d_ws;
    int* cnt = (int*)wsb;                       // [640]
    int* posCnt = cnt + NB * NCLS;              // [8]
    uint2* cand = (uint2*)(wsb + 4096);         // [640][CAP]
    float* cls_boxes = (float*)((char*)cand + (size_t)NB * NCLS * CAP * 8);  // [8][8000][4]
    uint32_t* posKey = (uint32_t*)(cls_boxes + (size_t)NB * NFLAT * 4);      // [8][8000]
    uint32_t* posFlat = posKey + (size_t)NB * NFLAT;                          // [8][8000]

    init_k<<<1, 256, 0, stream>>>(cnt);

    cand_scan<<<NB * BPB, 256, 0, stream>>>(reinterpret_cast<const float4*>(pred),
                                            cand, cnt);

    dim3 gb(NCLS, NB);
    nms_sel<<<gb, 256, 0, stream>>>(pred, cand, cnt, cls_boxes, posKey, posFlat,
                                    posCnt, dt);

    final_sel<<<NB, 256, 0, stream>>>(cls_boxes, posKey, posFlat, posCnt, out);
}

// Round 9
// 126.411 us; speedup vs baseline: 3.1135x; 1.2730x over previous
//
#include <hip/hip_runtime.h>
#include <math.h>
#include <stdint.h>

#define NANCH 49104
#define NCLS 80
#define KSEL 100
#define NFLAT (NCLS * KSEL)
#define PREDC 84
#define NB 8
#define ECAP 128
#define CAP 3072
#define BATF4 (NANCH * (PREDC / 4))        // 1,031,184 float4s per batch
#define BPB 128                             // cand_scan blocks per batch
#define LCAP 32                             // per-class LDS bucket cap
#define FASTN 512                           // fast-select list cap (n: mean 305, max ~360)
#define RMAX 8                              // FASTN/64 register candidates per lane
#define CNTP 16                             // counter cacheline padding (ints)
// z-threshold for candidates: score > sigmoid(2.5)=0.924; per-class 100th score
// sits at z=2.873±0.032 -> 2.5 is ~12 sigma below (exact fallback if ever violated)
#define THRL 2.5f

struct DimsTable { float d[5][9][2]; };
struct KT { uint32_t key; int tie; };

__device__ __forceinline__ uint32_t f2key(float f) {
    uint32_t u = __float_as_uint(f);
    return u ^ (uint32_t((int32_t)u >> 31) | 0x80000000u);
}
__device__ __forceinline__ float key2f(uint32_t k) {
    uint32_t u = (k & 0x80000000u) ? (k ^ 0x80000000u) : ~k;
    return __uint_as_float(u);
}
__device__ __forceinline__ float sigm(float x) { return 1.0f / (1.0f + expf(-x)); }

__device__ __forceinline__ void decode_box(const float4 pv, int n,
                                           const DimsTable& dt, float box[4]) {
    int lev, base, fw, stride;
    if (n < 36864)      { lev = 0; base = 0;     fw = 64; stride = 8;   }
    else if (n < 46080) { lev = 1; base = 36864; fw = 32; stride = 16;  }
    else if (n < 48384) { lev = 2; base = 46080; fw = 16; stride = 32;  }
    else if (n < 48960) { lev = 3; base = 48384; fw = 8;  stride = 64;  }
    else                { lev = 4; base = 48960; fw = 4;  stride = 128; }
    int i = n - base;
    int k = i % 9;
    int cell = i / 9;
    int xq = cell % fw, yq = cell / fw;
    float cx = ((float)xq + 0.5f) * (float)stride;
    float cy = ((float)yq + 0.5f) * (float)stride;
    float aw = dt.d[lev][k][0];
    float ah = dt.d[lev][k][1];
    float tx = __fmul_rn(pv.x, 0.1f);
    float ty = __fmul_rn(pv.y, 0.1f);
    float tw = __fmul_rn(pv.z, 0.2f);
    float th = __fmul_rn(pv.w, 0.2f);
    float px = __fadd_rn(__fmul_rn(tx, aw), cx);
    float py = __fadd_rn(__fmul_rn(ty, ah), cy);
    float pw = __fmul_rn(expf(tw), aw);
    float ph = __fmul_rn(expf(th), ah);
    float hw = __fmul_rn(pw, 0.5f);
    float hh = __fmul_rn(ph, 0.5f);
    box[0] = __fsub_rn(px, hw);
    box[1] = __fsub_rn(py, hh);
    box[2] = __fadd_rn(px, hw);
    box[3] = __fadd_rn(py, hh);
}

struct alignas(16) SelSh {
    int hist[4][2048];        // 32 KB; overlaid as uint64 list64[FASTN] in fast path
    int suffix[256];
    uint32_t candKey[KSEL];
    int candIdx[KSEL];
    uint32_t eIdx[ECAP];
    uint32_t sKey[KSEL];
    int sIdx[KSEL];
    int cntG, cntE, krem, newkrem, digit, flast, rmin;
    uint32_t prefix, thrKey;
};

// Exact top-min(K,N) by (key desc, tie asc); fills sh.sKey/sIdx sorted. 256 thr.
template <typename G>
__device__ int block_select(G get, int N, int K, SelSh& sh) {
    const int tid = threadIdx.x;
    const int wid = tid >> 6;
    int Ksel = (N < K) ? N : K;
    if (Ksel <= 0) return 0;

    if (N <= K) {
        if (tid < N) { KT e = get(tid); sh.candKey[tid] = e.key; sh.candIdx[tid] = e.tie; }
        __syncthreads();
        if (tid < N) {
            uint32_t mk = sh.candKey[tid]; int mi = sh.candIdx[tid];
            int rank = 0;
            for (int j = 0; j < N; ++j) {
                uint32_t kj = sh.candKey[j]; int ij = sh.candIdx[j];
                rank += (kj > mk) || (kj == mk && ij < mi);
            }
            sh.sKey[rank] = mk; sh.sIdx[rank] = mi;
        }
        __syncthreads();
        return Ksel;
    }

    if (tid == 0) { sh.krem = K; sh.prefix = 0; }
    for (int pass = 0; pass < 3; ++pass) {
        const int bins   = (pass == 2) ? 1024 : 2048;
        const int dshift = (pass == 0) ? 21 : (pass == 1 ? 10 : 0);
        const int fshift = (pass == 1) ? 21 : 10;
        const int dmask  = bins - 1;
        const bool multi = (pass == 0);
        if (multi) { for (int j = tid; j < 4 * 2048; j += 256) ((int*)sh.hist)[j] = 0; }
        else       { for (int j = tid; j < bins; j += 256) sh.hist[0][j] = 0; }
        __syncthreads();
        const uint32_t pref = sh.prefix;
        for (int i = tid; i < N; i += 256) {
            uint32_t key = get(i).key;
            if (pass == 0) {
                atomicAdd(&sh.hist[wid][(key >> dshift) & dmask], 1);
            } else if ((key >> fshift) == pref) {
                atomicAdd(&sh.hist[0][(key >> dshift) & dmask], 1);
            }
        }
        __syncthreads();
        if (multi) {
            for (int j = tid; j < bins; j += 256)
                sh.hist[0][j] += sh.hist[1][j] + sh.hist[2][j] + sh.hist[3][j];
            __syncthreads();
        }
        const int cpb = bins / 256;
        const int base = tid * cpb;
        int lsum = 0;
        for (int j = 0; j < cpb; ++j) lsum += sh.hist[0][base + j];
        sh.suffix[tid] = lsum;
        __syncthreads();
        for (int off = 1; off < 256; off <<= 1) {
            int v = (tid + off < 256) ? sh.suffix[tid + off] : 0;
            __syncthreads();
            sh.suffix[tid] += v;
            __syncthreads();
        }
        {
            int cum = sh.suffix[tid] - lsum;
            const int krem = sh.krem;
            for (int j = cpb - 1; j >= 0; --j) {
                int cnt = sh.hist[0][base + j];
                if (cnt > 0 && cum < krem && cum + cnt >= krem) {
                    sh.digit = base + j;
                    sh.newkrem = krem - cum;
                }
                cum += cnt;
            }
        }
        __syncthreads();
        if (tid == 0) {
            sh.krem = sh.newkrem;
            if (pass == 0)      sh.prefix = (uint32_t)sh.digit;
            else if (pass == 1) sh.prefix = (sh.prefix << 11) | (uint32_t)sh.digit;
            else                sh.thrKey = (sh.prefix << 10) | (uint32_t)sh.digit;
        }
        __syncthreads();
    }

    if (tid == 0) { sh.cntG = 0; sh.cntE = 0; }
    __syncthreads();
    const uint32_t thr = sh.thrKey;
    for (int i = tid; i < N; i += 256) {
        KT e = get(i);
        if (e.key > thr) {
            int g = atomicAdd(&sh.cntG, 1);
            sh.candKey[g] = e.key; sh.candIdx[g] = e.tie;
        } else if (e.key == thr) {
            int idx = atomicAdd(&sh.cntE, 1);
            if (idx < ECAP) sh.eIdx[idx] = (uint32_t)e.tie;
        }
    }
    __syncthreads();
    const int need = sh.krem;
    const int nG = K - need;
    if (sh.cntE <= ECAP) {
        const int ce = sh.cntE;
        if (tid < ce) {
            uint32_t my = sh.eIdx[tid];
            int rank = 0;
            for (int j = 0; j < ce; ++j) rank += (sh.eIdx[j] < my);
            if (rank < need) { sh.candKey[nG + rank] = thr; sh.candIdx[nG + rank] = (int)my; }
        }
    } else {
        if (tid == 0) sh.flast = -1;
        __syncthreads();
        for (int t = 0; t < need; ++t) {
            if (tid == 0) sh.rmin = 0x7FFFFFFF;
            __syncthreads();
            const int fl = sh.flast;
            int lmin = 0x7FFFFFFF;
            for (int i = tid; i < N; i += 256) {
                KT e = get(i);
                if (e.key == thr && e.tie > fl) lmin = min(lmin, e.tie);
            }
            atomicMin(&sh.rmin, lmin);
            __syncthreads();
            if (tid == 0) { sh.candKey[nG + t] = thr; sh.candIdx[nG + t] = sh.rmin; sh.flast = sh.rmin; }
            __syncthreads();
        }
    }
    __syncthreads();
    if (tid < K) {
        uint32_t mk = sh.candKey[tid]; int mi = sh.candIdx[tid];
        int rank = 0;
        for (int j = 0; j < K; ++j) {
            uint32_t kj = sh.candKey[j]; int ij = sh.candIdx[j];
            rank += (kj > mk) || (kj == mk && ij < mi);
        }
        sh.sKey[rank] = mk; sh.sIdx[rank] = mi;
    }
    __syncthreads();
    return Ksel;
}

// ---------- kernel 0: zero padded counters -----------------------------------
__global__ __launch_bounds__(256) void init_k(int* __restrict__ cnt) {
    for (int x = threadIdx.x; x < (NB * NCLS + NB) * CNTP; x += 256) cnt[x] = 0;
}

// ---------- kernel 1: coalesced scan + LDS buckets + bulk reservation --------
__device__ __forceinline__ void procf4(float4 p, int v, int b,
                                       int* lcnt, uint2 (*buck)[LCAP],
                                       int* cnt, uint2* cand) {
    uint32_t q = (uint32_t)v / 21u;
    uint32_t j = (uint32_t)v - q * 21u;
    if (j == 0u) return;
    bool c0 = p.x > THRL, c1 = p.y > THRL, c2 = p.z > THRL, c3 = p.w > THRL;
    if (!(c0 | c1 | c2 | c3)) return;
    uint32_t row = q - (uint32_t)b * (uint32_t)NANCH;
    int cbase = ((int)j - 1) * 4;
    float vv[4] = {p.x, p.y, p.z, p.w};
    bool pp[4] = {c0, c1, c2, c3};
#pragma unroll
    for (int k = 0; k < 4; ++k) {
        if (pp[k]) {
            int c = cbase + k;
            uint32_t key = f2key(sigm(vv[k]));
            int slot = atomicAdd(&lcnt[c], 1);
            if (slot < LCAP) {
                buck[c][slot] = make_uint2(key, row);
            } else {                       // rare: direct global reservation
                int bc = b * NCLS + c;
                int gs = atomicAdd(&cnt[bc * CNTP], 1);
                if (gs < CAP) cand[(size_t)bc * CAP + gs] = make_uint2(key, row);
            }
        }
    }
}

__global__ __launch_bounds__(256) void cand_scan(const float4* __restrict__ predv,
                                                 uint2* __restrict__ cand,
                                                 int* __restrict__ cnt) {
    __shared__ uint2 buck[NCLS][LCAP];     // 20 KB
    __shared__ int lcnt[NCLS];
    __shared__ int gbase[NCLS];

    const int tid = threadIdx.x;
    const int b = blockIdx.x / BPB;
    const int part = blockIdx.x - b * BPB;
    const int CH = (BATF4 + BPB - 1) / BPB;

    for (int j = tid; j < NCLS; j += 256) lcnt[j] = 0;
    __syncthreads();

    int s = b * BATF4 + part * CH;
    int e = b * BATF4 + BATF4;
    if (s + CH < e) e = s + CH;

    int v = s + tid;
    for (; v + 7 * 256 < e; v += 8 * 256) {   // 8 independent loads in flight
        float4 a0 = predv[v];
        float4 a1 = predv[v + 1 * 256];
        float4 a2 = predv[v + 2 * 256];
        float4 a3 = predv[v + 3 * 256];
        float4 a4 = predv[v + 4 * 256];
        float4 a5 = predv[v + 5 * 256];
        float4 a6 = predv[v + 6 * 256];
        float4 a7 = predv[v + 7 * 256];
        procf4(a0, v,           b, lcnt, buck, cnt, cand);
        procf4(a1, v + 1 * 256, b, lcnt, buck, cnt, cand);
        procf4(a2, v + 2 * 256, b, lcnt, buck, cnt, cand);
        procf4(a3, v + 3 * 256, b, lcnt, buck, cnt, cand);
        procf4(a4, v + 4 * 256, b, lcnt, buck, cnt, cand);
        procf4(a5, v + 5 * 256, b, lcnt, buck, cnt, cand);
        procf4(a6, v + 6 * 256, b, lcnt, buck, cnt, cand);
        procf4(a7, v + 7 * 256, b, lcnt, buck, cnt, cand);
    }
    for (; v < e; v += 256)
        procf4(predv[v], v, b, lcnt, buck, cnt, cand);
    __syncthreads();

    if (tid < NCLS) {
        int lc = lcnt[tid];
        if (lc > LCAP) lc = LCAP;
        gbase[tid] = (lc > 0) ? atomicAdd(&cnt[(b * NCLS + tid) * CNTP], lc) : 0;
    }
    __syncthreads();

    for (int x = tid; x < NCLS * LCAP; x += 256) {
        int c = x >> 5;                    // LCAP = 32
        int k = x & (LCAP - 1);
        int lc = lcnt[c];
        if (lc > LCAP) lc = LCAP;
        if (k < lc) {
            int gs = gbase[c] + k;
            if (gs < CAP)
                cand[(size_t)(b * NCLS + c) * CAP + gs] = buck[c][k];
        }
    }
}

// ---------- kernel 2: wave-split rank-select + parallel-IoU NMS --------------
__global__ __launch_bounds__(256) void nms_sel(const float* __restrict__ pred,
                                               const uint2* __restrict__ cand,
                                               const int* __restrict__ cnt,
                                               float* __restrict__ cls_boxes,
                                               uint32_t* __restrict__ posKey,
                                               uint32_t* __restrict__ posFlat,
                                               int* __restrict__ posCnt,
                                               DimsTable dt) {
    __shared__ SelSh sh;
    __shared__ uint16_t prank[4][FASTN];   // 4 KB partial ranks
    __shared__ float sbox[KSEL][4];
    __shared__ float sarea[KSEL];
    __shared__ int sconf[KSEL];
    __shared__ uint32_t sup[KSEL][4];
    __shared__ uint32_t keepm[4];
    __shared__ int baseSh;
    const int c = blockIdx.x;
    const int b = blockIdx.y;
    const int tid = threadIdx.x;
    const int bc = b * NCLS + c;
    const int n = cnt[bc * CNTP];

    if (n >= KSEL && n <= FASTN) {
        unsigned long long* list64 = (unsigned long long*)sh.hist;  // 4 KB used
        const uint2* src = cand + (size_t)bc * CAP;
        for (int x = tid; x < n; x += 256) {
            uint2 p = src[x];                                  // coalesced
            list64[x] = ((unsigned long long)p.x << 32) |
                        (unsigned long long)(~p.y);
        }
        __syncthreads();
        const int wid = tid >> 6;
        const int lane = tid & 63;
        // each wave holds ALL candidates in registers (8 u64/lane, static idx)
        unsigned long long cl[RMAX];
        int pr[RMAX];
#pragma unroll
        for (int r = 0; r < RMAX; ++r) {
            int i = r * 64 + lane;
            cl[r] = (i < n) ? list64[i] : 0xFFFFFFFFFFFFFFFFull;  // sentinel: never ranked
            pr[r] = 0;
        }
        // wave w streams only its quarter of the list (broadcast reads)
        const int js = (wid * n) >> 2;
        const int je = ((wid + 1) * n) >> 2;
        int j = js;
        for (; j + 3 < je; j += 4) {
            unsigned long long o0 = list64[j];
            unsigned long long o1 = list64[j + 1];
            unsigned long long o2 = list64[j + 2];
            unsigned long long o3 = list64[j + 3];
#pragma unroll
            for (int r = 0; r < RMAX; ++r)
                pr[r] += (o0 > cl[r]) + (o1 > cl[r]) + (o2 > cl[r]) + (o3 > cl[r]);
        }
        for (; j < je; ++j) {
            unsigned long long o = list64[j];
#pragma unroll
            for (int r = 0; r < RMAX; ++r) pr[r] += (o > cl[r]);
        }
#pragma unroll
        for (int r = 0; r < RMAX; ++r) {
            int i = r * 64 + lane;
            if (i < n) prank[wid][i] = (uint16_t)pr[r];
        }
        __syncthreads();
        // total rank = sum of the 4 partials; ranks are unique (distinct u64s)
        for (int i = tid; i < n; i += 256) {
            int rank = (int)prank[0][i] + (int)prank[1][i]
                     + (int)prank[2][i] + (int)prank[3][i];
            if (rank < KSEL) {
                unsigned long long e = list64[i];
                sh.sKey[rank] = (uint32_t)(e >> 32);
                sh.sIdx[rank] = (int)(~(uint32_t)e);
            }
        }
        __syncthreads();
    } else {
        // exact fallback: full strided scan (never taken on this data)
        const float* src = pred + (size_t)b * NANCH * PREDC + 4 + c;
        auto g = [src](int i) { KT e; e.key = f2key(sigm(src[(size_t)i * PREDC])); e.tie = i; return e; };
        block_select(g, NANCH, KSEL, sh);
    }

    // ---- decode the 100 boxes + conf flags (parallel) ----
    for (int x = tid; x < KSEL * 4; x += 256) ((uint32_t*)sup)[x] = 0;
    if (tid < KSEL) {
        int ni = sh.sIdx[tid];
        float4 pv = reinterpret_cast<const float4*>(pred)[((size_t)b * NANCH + ni) * (PREDC / 4)];
        float bx[4]; decode_box(pv, ni, dt, bx);
        sbox[tid][0] = bx[0]; sbox[tid][1] = bx[1];
        sbox[tid][2] = bx[2]; sbox[tid][3] = bx[3];
        sarea[tid] = __fmul_rn(__fsub_rn(bx[2], bx[0]), __fsub_rn(bx[3], bx[1]));
        sconf[tid] = (key2f(sh.sKey[tid]) > 0.05f) ? 1 : 0;
    }
    __syncthreads();

    // ---- parallel IoU suppression matrix (j > i bits only) ----
    for (int pidx = tid; pidx < KSEL * KSEL; pidx += 256) {
        int i = pidx / KSEL;
        int jj = pidx - i * KSEL;
        if (jj > i && sconf[i] && sconf[jj]) {
            float x1 = fmaxf(sbox[i][0], sbox[jj][0]);
            float y1 = fmaxf(sbox[i][1], sbox[jj][1]);
            float x2 = fminf(sbox[i][2], sbox[jj][2]);
            float y2 = fminf(sbox[i][3], sbox[jj][3]);
            float iw = fmaxf(__fsub_rn(x2, x1), 0.0f);
            float ih = fmaxf(__fsub_rn(y2, y1), 0.0f);
            float inter = __fmul_rn(iw, ih);
            float uni = __fsub_rn(__fadd_rn(sarea[i], sarea[jj]), inter);
            if (__fdiv_rn(inter, fmaxf(uni, 1e-8f)) > 0.5f)
                atomicOr(&sup[i][jj >> 5], 1u << (jj & 31));
        }
    }
    __syncthreads();

    // ---- greedy pass over the bitmask (single thread, registers) ----
    if (tid == 0) {
        uint32_t k0 = 0, k1 = 0, k2 = 0, k3 = 0;
        for (int i = 0; i < KSEL; ++i)
            if (sconf[i]) { if (i < 32) k0 |= 1u << i; else if (i < 64) k1 |= 1u << (i - 32);
                            else if (i < 96) k2 |= 1u << (i - 64); else k3 |= 1u << (i - 96); }
        for (int i = 0; i < KSEL; ++i) {
            uint32_t w = (i < 32) ? k0 : (i < 64) ? k1 : (i < 96) ? k2 : k3;
            if ((w >> (i & 31)) & 1u) {
                k0 &= ~sup[i][0]; k1 &= ~sup[i][1]; k2 &= ~sup[i][2]; k3 &= ~sup[i][3];
            }
        }
        keepm[0] = k0; keepm[1] = k1; keepm[2] = k2; keepm[3] = k3;
        baseSh = atomicAdd(&posCnt[b * CNTP],
                           __popc(k0) + __popc(k1) + __popc(k2) + __popc(k3));
    }
    __syncthreads();

    // ---- write boxes + append kept positives ----
    if (tid < KSEL) {
        reinterpret_cast<float4*>(cls_boxes)[(size_t)b * NFLAT + c * KSEL + tid] =
            make_float4(sbox[tid][0], sbox[tid][1], sbox[tid][2], sbox[tid][3]);
        int w = tid >> 5, bit = tid & 31;
        if ((keepm[w] >> bit) & 1u) {
            int off = __popc(keepm[w] & ((bit == 0) ? 0u : ((1u << bit) - 1u)));
            for (int ww = 0; ww < w; ++ww) off += __popc(keepm[ww]);
            posKey[(size_t)b * NFLAT + baseSh + off] = sh.sKey[tid];
            posFlat[(size_t)b * NFLAT + baseSh + off] = (uint32_t)(c * KSEL + tid);
        }
    }
}

// ---------- kernel 3: per-batch final top-100 over compacted positives -------
__global__ __launch_bounds__(256) void final_sel(const float* __restrict__ cls_boxes,
                                                 const uint32_t* __restrict__ posKey,
                                                 const uint32_t* __restrict__ posFlat,
                                                 const int* __restrict__ posCnt,
                                                 float* __restrict__ out) {
    __shared__ SelSh sh;
    const int b = blockIdx.x;
    const int tid = threadIdx.x;
    int m = posCnt[b * CNTP];
    if (m > NFLAT) m = NFLAT;
    const uint32_t* pk = posKey + (size_t)b * NFLAT;
    const uint32_t* pf = posFlat + (size_t)b * NFLAT;
    auto g = [pk, pf](int i) { KT e; e.key = pk[i]; e.tie = (int)pf[i]; return e; };
    int K = block_select(g, m, KSEL, sh);
    if (tid < KSEL) {
        float4 ob = make_float4(0.f, 0.f, 0.f, 0.f);
        float sv = 0.f, cv = 0.f;
        if (tid < K) {
            sv = key2f(sh.sKey[tid]);
            int flat = sh.sIdx[tid];
            ob = reinterpret_cast<const float4*>(cls_boxes)[(size_t)b * NFLAT + flat];
            cv = (float)(flat / KSEL);
        }
        reinterpret_cast<float4*>(out)[(size_t)b * KSEL + tid] = ob;
        out[NB * KSEL * 4 + b * KSEL + tid] = sv;
        out[NB * KSEL * 5 + b * KSEL + tid] = cv;
    }
    if (tid == 0) out[NB * KSEL * 6 + b] = (float)K;
}

// ---------- host launcher ----------------------------------------------------
extern "C" void kernel_launch(void* const* d_in, const int* in_sizes, int n_in,
                              void* d_out, int out_size, void* d_ws, size_t ws_size,
                              hipStream_t stream) {
    const float* pred = (const float*)d_in[1];
    float* out = (float*)d_out;

    DimsTable dt;
    const double areasd[5] = {1024.0, 4096.0, 16384.0, 65536.0, 262144.0};
    const double ratios[3] = {0.5, 1.0, 2.0};
    const double scales[3] = {1.0, pow(2.0, 1.0 / 3.0), pow(2.0, 2.0 / 3.0)};
    for (int l = 0; l < 5; ++l)
        for (int ri = 0; ri < 3; ++ri) {
            double ah = sqrt(areasd[l] / ratios[ri]);
            double aw = areasd[l] / ah;
            for (int si = 0; si < 3; ++si) {
                dt.d[l][ri * 3 + si][0] = (float)(aw * scales[si]);
                dt.d[l][ri * 3 + si][1] = (float)(ah * scales[si]);
            }
        }

    // workspace layout: ~17.4 MB (counters padded to one cacheline each)
    char* wsb = (char*)d_ws;
    int* cnt = (int*)wsb;                               // [640*CNTP]
    int* posCnt = cnt + NB * NCLS * CNTP;               // [8*CNTP]
    uint2* cand = (uint2*)(wsb + 64 * 1024);            // [640][CAP]
    float* cls_boxes = (float*)((char*)cand + (size_t)NB * NCLS * CAP * 8);  // [8][8000][4]
    uint32_t* posKey = (uint32_t*)(cls_boxes + (size_t)NB * NFLAT * 4);      // [8][8000]
    uint32_t* posFlat = posKey + (size_t)NB * NFLAT;                          // [8][8000]

    init_k<<<1, 256, 0, stream>>>(cnt);

    cand_scan<<<NB * BPB, 256, 0, stream>>>(reinterpret_cast<const float4*>(pred),
                                            cand, cnt);

    dim3 gb(NCLS, NB);
    nms_sel<<<gb, 256, 0, stream>>>(pred, cand, cnt, cls_boxes, posKey, posFlat,
                                    posCnt, dt);

    final_sel<<<NB, 256, 0, stream>>>(cls_boxes, posKey, posFlat, posCnt, out);
}